// Round 4
// baseline (1416.464 us; speedup 1.0000x reference)
//
#include <hip/hip_runtime.h>
#include <cstdint>

// NonLocalBlock MI355X — flash-fused attention version (fp16 MFMA, fp32 accum).
//   k_init: weights->fp16, zero BN stats
//   k_xt:   x [b][c][n] f32 -> xt [b][n][c] fp16
//   k_proj: fused QKV: v [b][o][n], q/k [b][n][i]
//   k_flash: per (b, 128-row q-tile, 256-col C-half): loop 32 K/V tiles:
//            S=QK^T * rd-table, online softmax (LDS-combined), P->LDS fp16,
//            PV accumulate in regs; epilogue y = acc / rowsum  -> y [b][n][c]
//   k_u:    u = Wu @ y^T + fused BN partial sums
//   k_bnfin, k_out: BN finalize; relu(u*sc+sh+x)
// LDS in k_flash: K 32K + V 64K + P/Q 32K + rdtable 16K + stats 2K = 146KB.

typedef unsigned short u16;
typedef unsigned int u32;
using half8 = __attribute__((ext_vector_type(8))) _Float16;
using f32x4 = __attribute__((ext_vector_type(4))) float;

#define B_ 8
#define N_ 4096
#define C_ 512
#define I_ 128

__device__ __forceinline__ u16 f2h(float f) {
  return __builtin_bit_cast(u16, (_Float16)f);
}
__device__ __forceinline__ float h2f(u16 v) {
  return (float)__builtin_bit_cast(_Float16, v);
}

__device__ __forceinline__ void gld16(const void* g, void* l) {
  __builtin_amdgcn_global_load_lds((const __attribute__((address_space(1))) u32*)g,
                                   (__attribute__((address_space(3))) u32*)l, 16, 0, 0);
}

__device__ __forceinline__ f32x4 mfma16(half8 a, half8 b, f32x4 c) {
  return __builtin_amdgcn_mfma_f32_16x16x32_f16(a, b, c, 0, 0, 0);
}

// ---------------- common 128x128 BT-GEMM core (BK=32, 256 threads, 4 waves) ---
__device__ __forceinline__ void gemm128_bt(const u16* __restrict__ Ap, int lda,
                                           const u16* __restrict__ Bp, int ldb,
                                           int K, u16* As, u16* Bs,
                                           f32x4 (&acc)[4][4])
{
  const int tid = threadIdx.x;
  const int w = tid >> 6, l = tid & 63;
  const int wr = w >> 1, wc = w & 1;
  const int srow = tid >> 2, schunk = tid & 3;

  for (int k0 = 0; k0 < K; k0 += 32) {
    __syncthreads();
#pragma unroll
    for (int i = 0; i < 2; ++i) {
      int r = i * 64 + srow;
      int sc = (schunk ^ (r & 3) ^ ((r >> 2) & 3)) << 3;
      gld16(Ap + (size_t)r * lda + k0 + sc, As + i * 2048 + w * 512);
      gld16(Bp + (size_t)r * ldb + k0 + sc, Bs + i * 2048 + w * 512);
    }
    __syncthreads();

    half8 af[4], bf[4];
#pragma unroll
    for (int mi = 0; mi < 4; ++mi) {
      int rl = wr * 64 + mi * 16 + (l & 15);
      int ch = (l >> 4) ^ (rl & 3) ^ ((rl >> 2) & 3);
      af[mi] = *(const half8*)(As + rl * 32 + ch * 8);
    }
#pragma unroll
    for (int nj = 0; nj < 4; ++nj) {
      int rl = wc * 64 + nj * 16 + (l & 15);
      int ch = (l >> 4) ^ (rl & 3) ^ ((rl >> 2) & 3);
      bf[nj] = *(const half8*)(Bs + rl * 32 + ch * 8);
    }
#pragma unroll
    for (int mi = 0; mi < 4; ++mi)
#pragma unroll
      for (int nj = 0; nj < 4; ++nj)
        acc[mi][nj] = mfma16(af[mi], bf[nj], acc[mi][nj]);
  }
}

// ---------------- init ---------------------------------------------------------
__global__ __launch_bounds__(256) void k_init(const float* __restrict__ Wv,
    const float* __restrict__ Wq, const float* __restrict__ Wk,
    const float* __restrict__ Wu, u16* __restrict__ wqkv, u16* __restrict__ wu,
    float* __restrict__ stats)
{
  int i = blockIdx.x * 256 + threadIdx.x;
  if (i < 768 * 512) {
    int r = i >> 9, c = i & 511;
    float val = (r < 512) ? Wv[i] : (r < 640 ? Wq[(r - 512) * 512 + c]
                                             : Wk[(r - 640) * 512 + c]);
    wqkv[i] = f2h(val);
  }
  if (i < 512 * 512) wu[i] = f2h(Wu[i]);
  if (i < 1024) stats[i] = 0.f;
}

// ---------------- x transpose+convert ----------------------------------------
__global__ __launch_bounds__(256) void k_xt(const float* __restrict__ x,
                                            u16* __restrict__ xt)
{
  __shared__ float t[64][65];
  int id = blockIdx.x;
  int b = id >> 9, cg = (id >> 6) & 7, ng = id & 63;
  int c0 = cg * 64, n0 = ng * 64;
  int tid = threadIdx.x;
  const float* xs = x + ((size_t)b * C_ + c0) * N_ + n0;
#pragma unroll
  for (int p = 0; p < 16; ++p) {
    int idx = p * 256 + tid; int r = idx >> 6, cl = idx & 63;
    t[r][cl] = xs[(size_t)r * N_ + cl];
  }
  __syncthreads();
  u16* xd = xt + ((size_t)b * N_ + n0) * C_ + c0;
#pragma unroll
  for (int p = 0; p < 16; ++p) {
    int idx = p * 256 + tid; int r = idx >> 6, cl = idx & 63;
    xd[(size_t)r * C_ + cl] = f2h(t[cl][r]);
  }
}

// ---------------- fused QKV projection ---------------------------------------
__global__ __launch_bounds__(256) void k_proj(const u16* __restrict__ wqkv,
    const u16* __restrict__ xt, u16* __restrict__ v, u16* __restrict__ q,
    u16* __restrict__ kk)
{
  __shared__ u16 As[128 * 32], Bs[128 * 32];
  int id = blockIdx.x;
  int bm = id % 6; int rest = id / 6; int bn = rest & 31; int b = rest >> 5;
  const u16* Ap = wqkv + bm * 128 * 512;
  const u16* Bp = xt + ((size_t)b * N_ + bn * 128) * C_;
  f32x4 acc[4][4];
#pragma unroll
  for (int a1 = 0; a1 < 4; ++a1)
#pragma unroll
    for (int a2 = 0; a2 < 4; ++a2) acc[a1][a2] = f32x4{0.f, 0.f, 0.f, 0.f};
  gemm128_bt(Ap, 512, Bp, 512, 512, As, Bs, acc);

  int tid = threadIdx.x, w = tid >> 6, l = tid & 63, wr = w >> 1, wc = w & 1;
#pragma unroll
  for (int mi = 0; mi < 4; ++mi)
#pragma unroll
    for (int nj = 0; nj < 4; ++nj)
#pragma unroll
      for (int e = 0; e < 4; ++e) {
        int gr = bm * 128 + wr * 64 + mi * 16 + ((l >> 4) << 2) + e;
        int gc = bn * 128 + wc * 64 + nj * 16 + (l & 15);
        u16 bv = f2h(acc[mi][nj][e]);
        if (bm < 4)       v[((size_t)b * C_ + gr) * N_ + gc] = bv;
        else if (bm == 4) q[((size_t)b * N_ + gc) * I_ + (gr - 512)] = bv;
        else              kk[((size_t)b * N_ + gc) * I_ + (gr - 640)] = bv;
      }
}

// ---------------- flash attention --------------------------------------------
// Grid: 512 = ((b*32)+nt)*2+ch. Block: 512 threads = 8 waves (wr 0..3 x wc 0..1).
// Per wave: S quadrant 32x64; PV output 32 rows x 128 cols (of the 256-col half).
__global__ __launch_bounds__(512, 2) void k_flash(const u16* __restrict__ q,
    const u16* __restrict__ kk, const u16* __restrict__ v, u16* __restrict__ y)
{
  __shared__ u16 Kt[128 * 128];     // K-tile: [m-row][i], 256B rows, xor swz
  __shared__ u16 Vt[256 * 128];     // V-tile: [ch-row][m], 256B rows, xor swz
  __shared__ u16 Pt[128 * 128];     // P (and initially Q): [n-row][m/i], swz
  __shared__ float rdt[4096];       // 1/(1+sqrt(dx^2+dy^2)), [|dx|*64+|dy|]
  __shared__ float smax[2][128], ssum[2][128];

  int id = blockIdx.x;
  int ch = id & 1, nt = (id >> 1) & 31, b = id >> 6;
  int tid = threadIdx.x, w = tid >> 6, l = tid & 63;
  int wr = w >> 1, wc = w & 1;
  int l15 = l & 15, lh = l >> 4;

  const u16* qb = q  + ((size_t)b * N_ + nt * 128) * I_;
  const u16* kb = kk + (size_t)b * N_ * I_;
  const u16* vb = v  + ((size_t)b * C_ + ch * 256) * N_;

  // distance table
  for (int i = tid; i < 4096; i += 512) {
    float ddx = (float)(i >> 6), ddy = (float)(i & 63);
    rdt[i] = 1.0f / (1.0f + sqrtf(ddx * ddx + ddy * ddy));
  }
  // stage Q into Pt (pre-swizzled source -> linear LDS dest)
#pragma unroll
  for (int i = 0; i < 4; ++i) {
    int slot = i * 512 + tid;
    int row = slot >> 4, pp = (slot & 15) ^ (row & 7);
    gld16(qb + row * I_ + pp * 8, (char*)Pt + i * 8192 + w * 1024);
  }
  asm volatile("s_waitcnt vmcnt(0)" ::: "memory");
  __syncthreads();

  // Q A-frags (rows wr*32 .. +32), kept in registers for all 32 m-steps
  half8 qf[2][4];
#pragma unroll
  for (int mi = 0; mi < 2; ++mi)
#pragma unroll
    for (int kc = 0; kc < 4; ++kc) {
      int row = wr * 32 + mi * 16 + l15;
      int byte = (((row << 8) + kc * 64 + (lh << 4))) ^ ((row & 7) << 4);
      qf[mi][kc] = *(const half8*)((const char*)Pt + byte);
    }
  __syncthreads();   // Q reads done; Pt becomes the P buffer

  float mrow[2][4], lrow[2][4];
  f32x4 acc[2][8];
#pragma unroll
  for (int mi = 0; mi < 2; ++mi)
#pragma unroll
    for (int e = 0; e < 4; ++e) { mrow[mi][e] = -3e38f; lrow[mi][e] = 0.f; }
#pragma unroll
  for (int mi = 0; mi < 2; ++mi)
#pragma unroll
    for (int nj = 0; nj < 8; ++nj) acc[mi][nj] = f32x4{0.f, 0.f, 0.f, 0.f};

#pragma unroll 1
  for (int mt = 0; mt < 32; ++mt) {
    __syncthreads();                               // B1: prev-iter LDS reads done
    // stage K-tile (32KB) and V-tile (64KB)
#pragma unroll
    for (int i = 0; i < 4; ++i) {
      int slot = i * 512 + tid;
      int row = slot >> 4, pp = (slot & 15) ^ (row & 7);
      gld16(kb + (size_t)(mt * 128 + row) * I_ + pp * 8,
            (char*)Kt + i * 8192 + w * 1024);
    }
#pragma unroll
    for (int i = 0; i < 8; ++i) {
      int slot = i * 512 + tid;
      int row = slot >> 4, pp = (slot & 15) ^ (row & 7);
      gld16(vb + (size_t)row * N_ + mt * 128 + pp * 8,
            (char*)Vt + i * 8192 + w * 1024);
    }
    asm volatile("s_waitcnt vmcnt(0)" ::: "memory");
    __syncthreads();                               // B2: K,V staged

    // ---- QK^T: S quadrant (rows wr*32+.., cols wc*64+..) ----
    f32x4 s[2][4];
#pragma unroll
    for (int mi = 0; mi < 2; ++mi)
#pragma unroll
      for (int nj = 0; nj < 4; ++nj) s[mi][nj] = f32x4{0.f, 0.f, 0.f, 0.f};
#pragma unroll
    for (int kc = 0; kc < 4; ++kc) {
      half8 bf[4];
#pragma unroll
      for (int nj = 0; nj < 4; ++nj) {
        int row = wc * 64 + nj * 16 + l15;
        int byte = ((row << 8) + kc * 64 + (lh << 4)) ^ ((row & 7) << 4);
        bf[nj] = *(const half8*)((const char*)Kt + byte);
      }
#pragma unroll
      for (int mi = 0; mi < 2; ++mi)
#pragma unroll
        for (int nj = 0; nj < 4; ++nj)
          s[mi][nj] = mfma16(qf[mi][kc], bf[nj], s[mi][nj]);
    }

    // ---- apply 1/(1+dist) from table ----
#pragma unroll
    for (int mi = 0; mi < 2; ++mi) {
      int dxv = 2 * nt + ((wr * 2 + mi) >> 2) - 2 * mt - wc;
      int adx = dxv < 0 ? -dxv : dxv;
      int rbase = ((wr * 32 + mi * 16) & 63) + (lh << 2);
#pragma unroll
      for (int nj = 0; nj < 4; ++nj)
#pragma unroll
        for (int e = 0; e < 4; ++e) {
          int dy = rbase + e - (nj * 16 + l15);
          int ady = dy < 0 ? -dy : dy;
          s[mi][nj][e] *= rdt[(adx << 6) + ady];
        }
    }

    // ---- online softmax: partial rowmax -> LDS combine ----
    float pm[2][4];
#pragma unroll
    for (int mi = 0; mi < 2; ++mi)
#pragma unroll
      for (int e = 0; e < 4; ++e) {
        float m0 = fmaxf(fmaxf(s[mi][0][e], s[mi][1][e]),
                         fmaxf(s[mi][2][e], s[mi][3][e]));
#pragma unroll
        for (int d = 1; d < 16; d <<= 1) m0 = fmaxf(m0, __shfl_xor(m0, d, 64));
        pm[mi][e] = m0;
        int row = wr * 32 + mi * 16 + (lh << 2) + e;
        smax[wc][row] = m0;
      }
    __syncthreads();                               // B3: smax ready

    float alpha[2][4];
#pragma unroll
    for (int mi = 0; mi < 2; ++mi)
#pragma unroll
      for (int e = 0; e < 4; ++e) {
        int row = wr * 32 + mi * 16 + (lh << 2) + e;
        float cand = fmaxf(smax[0][row], smax[1][row]);
        float mnew = fmaxf(mrow[mi][e], cand);
        alpha[mi][e] = __expf(mrow[mi][e] - mnew);
        mrow[mi][e] = mnew;
      }

    // ---- P = exp(S - m), write to Pt, partial rowsum ----
    float ps[2][4];
#pragma unroll
    for (int mi = 0; mi < 2; ++mi)
#pragma unroll
      for (int e = 0; e < 4; ++e) ps[mi][e] = 0.f;
#pragma unroll
    for (int mi = 0; mi < 2; ++mi)
#pragma unroll
      for (int nj = 0; nj < 4; ++nj)
#pragma unroll
        for (int e = 0; e < 4; ++e) {
          float p = __expf(s[mi][nj][e] - mrow[mi][e]);
          ps[mi][e] += p;
          int row = wr * 32 + mi * 16 + (lh << 2) + e;
          int col = wc * 64 + nj * 16 + l15;
          int byte = ((row << 8) + (col << 1)) ^ ((row & 7) << 4);
          *(u16*)((char*)Pt + byte) = f2h(p);
        }
#pragma unroll
    for (int mi = 0; mi < 2; ++mi)
#pragma unroll
      for (int e = 0; e < 4; ++e) {
        float s0 = ps[mi][e];
#pragma unroll
        for (int d = 1; d < 16; d <<= 1) s0 += __shfl_xor(s0, d, 64);
        int row = wr * 32 + mi * 16 + (lh << 2) + e;
        ssum[wc][row] = s0;
      }
    __syncthreads();                               // B4: P + ssum ready

#pragma unroll
    for (int mi = 0; mi < 2; ++mi)
#pragma unroll
      for (int e = 0; e < 4; ++e) {
        int row = wr * 32 + mi * 16 + (lh << 2) + e;
        float rs = ssum[0][row] + ssum[1][row];
        lrow[mi][e] = lrow[mi][e] * alpha[mi][e] + rs;
      }
#pragma unroll
    for (int mi = 0; mi < 2; ++mi)
#pragma unroll
      for (int nj = 0; nj < 8; ++nj)
#pragma unroll
        for (int e = 0; e < 4; ++e) acc[mi][nj][e] *= alpha[mi][e];

    // ---- PV: acc += P @ V^T (K = 128 m) ----
#pragma unroll
    for (int kc = 0; kc < 4; ++kc) {
      half8 pa[2];
#pragma unroll
      for (int mi = 0; mi < 2; ++mi) {
        int row = wr * 32 + mi * 16 + l15;
        int byte = ((row << 8) + kc * 64 + (lh << 4)) ^ ((row & 7) << 4);
        pa[mi] = *(const half8*)((const char*)Pt + byte);
      }
#pragma unroll
      for (int nj = 0; nj < 8; ++nj) {
        int row = wc * 128 + nj * 16 + l15;
        int byte = ((row << 8) + kc * 64 + (lh << 4)) ^ ((row & 7) << 4);
        half8 vf = *(const half8*)((const char*)Vt + byte);
#pragma unroll
        for (int mi = 0; mi < 2; ++mi)
          acc[mi][nj] = mfma16(pa[mi], vf, acc[mi][nj]);
      }
    }
  }

  // ---- epilogue: y = acc / rowsum ----
#pragma unroll
  for (int mi = 0; mi < 2; ++mi)
#pragma unroll
    for (int e = 0; e < 4; ++e) {
      float inv = 1.0f / lrow[mi][e];
      int gn = nt * 128 + wr * 32 + mi * 16 + (lh << 2) + e;
#pragma unroll
      for (int nj = 0; nj < 8; ++nj) {
        int gc = ch * 256 + wc * 128 + nj * 16 + l15;
        y[((size_t)b * N_ + gn) * C_ + gc] = f2h(acc[mi][nj][e] * inv);
      }
    }
}

// ---------------- u = Wu @ y^T, + BN partial stats ----------------------------
__global__ __launch_bounds__(256) void k_u(const u16* __restrict__ wu,
    const u16* __restrict__ y, u16* __restrict__ uo, float* __restrict__ stats)
{
  __shared__ u16 As[128 * 32], Bs[128 * 32];
  int id = blockIdx.x;
  int bm = id & 3, bn = (id >> 2) & 31, b = id >> 7;
  const u16* Ap = wu + bm * 128 * 512;
  const u16* Bp = y + (size_t)b * N_ * C_ + (size_t)bn * 128 * C_;
  f32x4 acc[4][4];
#pragma unroll
  for (int a1 = 0; a1 < 4; ++a1)
#pragma unroll
    for (int a2 = 0; a2 < 4; ++a2) acc[a1][a2] = f32x4{0.f, 0.f, 0.f, 0.f};
  gemm128_bt(Ap, 512, Bp, 512, 512, As, Bs, acc);

  int tid = threadIdx.x, w = tid >> 6, l = tid & 63, wr = w >> 1, wc = w & 1;
#pragma unroll
  for (int mi = 0; mi < 4; ++mi)
#pragma unroll
    for (int e = 0; e < 4; ++e) {
      int gr = bm * 128 + wr * 64 + mi * 16 + ((l >> 4) << 2) + e;
      float s = 0.f, s2 = 0.f;
#pragma unroll
      for (int nj = 0; nj < 4; ++nj) {
        float val = acc[mi][nj][e];
        int gc = bn * 128 + wc * 64 + nj * 16 + (l & 15);
        uo[((size_t)b * C_ + gr) * N_ + gc] = f2h(val);
        s += val; s2 += val * val;
      }
#pragma unroll
      for (int d = 1; d < 16; d <<= 1) {
        s  += __shfl_xor(s, d, 64);
        s2 += __shfl_xor(s2, d, 64);
      }
      if ((l & 15) == 0) {
        atomicAdd(stats + gr, s);
        atomicAdd(stats + 512 + gr, s2);
      }
    }
}

// ---------------- BN finalize -------------------------------------------------
__global__ __launch_bounds__(256) void k_bnfin(const float* __restrict__ stats,
    const float* __restrict__ gamma, const float* __restrict__ beta,
    float* __restrict__ coef)
{
  int c = blockIdx.x * 256 + threadIdx.x;
  if (c < 512) {
    const float inv = 1.0f / (float)(B_ * N_);
    float mean = stats[c] * inv;
    float var = stats[512 + c] * inv - mean * mean;
    float sc = gamma[c] * rsqrtf(var + 1e-5f);
    coef[c] = sc;
    coef[512 + c] = beta[c] - mean * sc;
  }
}

// ---------------- epilogue: relu(u_bn + x) ------------------------------------
__global__ __launch_bounds__(256) void k_out(const u16* __restrict__ uo,
    const float* __restrict__ x, const float* __restrict__ coef,
    float* __restrict__ out)
{
  int t = blockIdx.x * 256 + threadIdx.x;
  size_t base = (size_t)t * 8;
  int c = (t >> 9) & 511;
  float sc = coef[c], sh = coef[512 + c];
  using short8 = __attribute__((ext_vector_type(8))) short;
  short8 uv = *(const short8*)(uo + base);
  const float4* xp = (const float4*)(x + base);
  float4 x0 = xp[0], x1 = xp[1];
  float4 o0, o1;
  o0.x = fmaxf(h2f((u16)uv[0]) * sc + sh + x0.x, 0.f);
  o0.y = fmaxf(h2f((u16)uv[1]) * sc + sh + x0.y, 0.f);
  o0.z = fmaxf(h2f((u16)uv[2]) * sc + sh + x0.z, 0.f);
  o0.w = fmaxf(h2f((u16)uv[3]) * sc + sh + x0.w, 0.f);
  o1.x = fmaxf(h2f((u16)uv[4]) * sc + sh + x1.x, 0.f);
  o1.y = fmaxf(h2f((u16)uv[5]) * sc + sh + x1.y, 0.f);
  o1.z = fmaxf(h2f((u16)uv[6]) * sc + sh + x1.z, 0.f);
  o1.w = fmaxf(h2f((u16)uv[7]) * sc + sh + x1.w, 0.f);
  float4* op = (float4*)(out + base);
  op[0] = o0; op[1] = o1;
}

// ---------------- launcher ----------------------------------------------------
extern "C" void kernel_launch(void* const* d_in, const int* in_sizes, int n_in,
                              void* d_out, int out_size, void* d_ws, size_t ws_size,
                              hipStream_t stream)
{
  const float* x  = (const float*)d_in[0];
  const float* Wv = (const float*)d_in[1];
  const float* Wq = (const float*)d_in[2];
  const float* Wk = (const float*)d_in[3];
  const float* Wu = (const float*)d_in[4];
  const float* gm = (const float*)d_in[5];
  const float* bt = (const float*)d_in[6];

  char* ws = (char*)d_ws;
  u16* xt       = (u16*)(ws + 0);            // 33,554,432 (xt, then y)
  u16* y        = xt;
  u16* v        = (u16*)(ws + 33554432);     // 33,554,432
  u16* q        = (u16*)(ws + 67108864);     //  8,388,608
  u16* kk       = (u16*)(ws + 75497472);     //  8,388,608
  u16* wqkv     = (u16*)(ws + 83886080);     //    786,432
  u16* wu       = (u16*)(ws + 84672512);     //    524,288
  float* stats  = (float*)(ws + 85196800);   //      4,096
  float* coef   = (float*)(ws + 85200896);   //      4,096
  u16* uo       = (u16*)(ws + 85204992);     // 33,554,432
  // total ~113 MB

  k_init<<<1536, 256, 0, stream>>>(Wv, Wq, Wk, Wu, wqkv, wu, stats);
  k_xt<<<4096, 256, 0, stream>>>(x, xt);
  k_proj<<<1536, 256, 0, stream>>>(wqkv, xt, v, q, kk);
  k_flash<<<512, 512, 0, stream>>>(q, kk, v, y);
  k_u<<<1024, 256, 0, stream>>>(wu, y, uo, stats);
  k_bnfin<<<2, 256, 0, stream>>>(stats, gm, bt, coef);
  k_out<<<8192, 256, 0, stream>>>(uo, x, coef, (float*)d_out);
}

// Round 5
// 880.933 us; speedup vs baseline: 1.6079x; 1.6079x over previous
//
#include <hip/hip_runtime.h>
#include <cstdint>

// NonLocalBlock MI355X — flash-fused attention v2 (fp16 MFMA, fp32 accum).
//   k_init: weights->fp16, zero BN stats
//   k_xt:   x [b][c][n] f32 -> xt [b][n][c] fp16
//   k_proj: fused QKV: v [b][o][n], q/k [b][n][i]
//   k_flash2: grid (b, nt 128-q-rows, chq 128-ch-quarter), 8 waves:
//            64 iters over 64-wide K/V tiles, double-buffered LDS with
//            counted vmcnt(4) prefetch; wave-local online softmax
//            (16 q-rows/wave); dist factor computed (dy loop-invariant,
//            dx decrements); P in LDS (wave-private), PV into 32-VGPR acc.
//   k_u:    u = Wu @ y^T + fused BN partial sums
//   k_bnfin, k_out: BN finalize; relu(u*sc+sh+x)
// LDS k_flash2: Kt 2x16K + Vt 2x16K + Pt 16K = 80KB -> 2 blocks/CU target.

typedef unsigned short u16;
typedef unsigned int u32;
using half8 = __attribute__((ext_vector_type(8))) _Float16;
using f32x4 = __attribute__((ext_vector_type(4))) float;

#define B_ 8
#define N_ 4096
#define C_ 512
#define I_ 128

__device__ __forceinline__ u16 f2h(float f) {
  return __builtin_bit_cast(u16, (_Float16)f);
}
__device__ __forceinline__ float h2f(u16 v) {
  return (float)__builtin_bit_cast(_Float16, v);
}

__device__ __forceinline__ void gld16(const void* g, void* l) {
  __builtin_amdgcn_global_load_lds((const __attribute__((address_space(1))) u32*)g,
                                   (__attribute__((address_space(3))) u32*)l, 16, 0, 0);
}

__device__ __forceinline__ f32x4 mfma16(half8 a, half8 b, f32x4 c) {
  return __builtin_amdgcn_mfma_f32_16x16x32_f16(a, b, c, 0, 0, 0);
}

// ---------------- common 128x128 BT-GEMM core (BK=32, 256 threads, 4 waves) ---
__device__ __forceinline__ void gemm128_bt(const u16* __restrict__ Ap, int lda,
                                           const u16* __restrict__ Bp, int ldb,
                                           int K, u16* As, u16* Bs,
                                           f32x4 (&acc)[4][4])
{
  const int tid = threadIdx.x;
  const int w = tid >> 6, l = tid & 63;
  const int wr = w >> 1, wc = w & 1;
  const int srow = tid >> 2, schunk = tid & 3;

  for (int k0 = 0; k0 < K; k0 += 32) {
    __syncthreads();
#pragma unroll
    for (int i = 0; i < 2; ++i) {
      int r = i * 64 + srow;
      int sc = (schunk ^ (r & 3) ^ ((r >> 2) & 3)) << 3;
      gld16(Ap + (size_t)r * lda + k0 + sc, As + i * 2048 + w * 512);
      gld16(Bp + (size_t)r * ldb + k0 + sc, Bs + i * 2048 + w * 512);
    }
    __syncthreads();

    half8 af[4], bf[4];
#pragma unroll
    for (int mi = 0; mi < 4; ++mi) {
      int rl = wr * 64 + mi * 16 + (l & 15);
      int ch = (l >> 4) ^ (rl & 3) ^ ((rl >> 2) & 3);
      af[mi] = *(const half8*)(As + rl * 32 + ch * 8);
    }
#pragma unroll
    for (int nj = 0; nj < 4; ++nj) {
      int rl = wc * 64 + nj * 16 + (l & 15);
      int ch = (l >> 4) ^ (rl & 3) ^ ((rl >> 2) & 3);
      bf[nj] = *(const half8*)(Bs + rl * 32 + ch * 8);
    }
#pragma unroll
    for (int mi = 0; mi < 4; ++mi)
#pragma unroll
      for (int nj = 0; nj < 4; ++nj)
        acc[mi][nj] = mfma16(af[mi], bf[nj], acc[mi][nj]);
  }
}

// ---------------- init ---------------------------------------------------------
__global__ __launch_bounds__(256) void k_init(const float* __restrict__ Wv,
    const float* __restrict__ Wq, const float* __restrict__ Wk,
    const float* __restrict__ Wu, u16* __restrict__ wqkv, u16* __restrict__ wu,
    float* __restrict__ stats)
{
  int i = blockIdx.x * 256 + threadIdx.x;
  if (i < 768 * 512) {
    int r = i >> 9, c = i & 511;
    float val = (r < 512) ? Wv[i] : (r < 640 ? Wq[(r - 512) * 512 + c]
                                             : Wk[(r - 640) * 512 + c]);
    wqkv[i] = f2h(val);
  }
  if (i < 512 * 512) wu[i] = f2h(Wu[i]);
  if (i < 1024) stats[i] = 0.f;
}

// ---------------- x transpose+convert ----------------------------------------
__global__ __launch_bounds__(256) void k_xt(const float* __restrict__ x,
                                            u16* __restrict__ xt)
{
  __shared__ float t[64][65];
  int id = blockIdx.x;
  int b = id >> 9, cg = (id >> 6) & 7, ng = id & 63;
  int c0 = cg * 64, n0 = ng * 64;
  int tid = threadIdx.x;
  const float* xs = x + ((size_t)b * C_ + c0) * N_ + n0;
#pragma unroll
  for (int p = 0; p < 16; ++p) {
    int idx = p * 256 + tid; int r = idx >> 6, cl = idx & 63;
    t[r][cl] = xs[(size_t)r * N_ + cl];
  }
  __syncthreads();
  u16* xd = xt + ((size_t)b * N_ + n0) * C_ + c0;
#pragma unroll
  for (int p = 0; p < 16; ++p) {
    int idx = p * 256 + tid; int r = idx >> 6, cl = idx & 63;
    xd[(size_t)r * C_ + cl] = f2h(t[cl][r]);
  }
}

// ---------------- fused QKV projection ---------------------------------------
__global__ __launch_bounds__(256) void k_proj(const u16* __restrict__ wqkv,
    const u16* __restrict__ xt, u16* __restrict__ v, u16* __restrict__ q,
    u16* __restrict__ kk)
{
  __shared__ u16 As[128 * 32], Bs[128 * 32];
  int id = blockIdx.x;
  int bm = id % 6; int rest = id / 6; int bn = rest & 31; int b = rest >> 5;
  const u16* Ap = wqkv + bm * 128 * 512;
  const u16* Bp = xt + ((size_t)b * N_ + bn * 128) * C_;
  f32x4 acc[4][4];
#pragma unroll
  for (int a1 = 0; a1 < 4; ++a1)
#pragma unroll
    for (int a2 = 0; a2 < 4; ++a2) acc[a1][a2] = f32x4{0.f, 0.f, 0.f, 0.f};
  gemm128_bt(Ap, 512, Bp, 512, 512, As, Bs, acc);

  int tid = threadIdx.x, w = tid >> 6, l = tid & 63, wr = w >> 1, wc = w & 1;
#pragma unroll
  for (int mi = 0; mi < 4; ++mi)
#pragma unroll
    for (int nj = 0; nj < 4; ++nj)
#pragma unroll
      for (int e = 0; e < 4; ++e) {
        int gr = bm * 128 + wr * 64 + mi * 16 + ((l >> 4) << 2) + e;
        int gc = bn * 128 + wc * 64 + nj * 16 + (l & 15);
        u16 bv = f2h(acc[mi][nj][e]);
        if (bm < 4)       v[((size_t)b * C_ + gr) * N_ + gc] = bv;
        else if (bm == 4) q[((size_t)b * N_ + gc) * I_ + (gr - 512)] = bv;
        else              kk[((size_t)b * N_ + gc) * I_ + (gr - 640)] = bv;
      }
}

// ---------------- flash attention v2 -----------------------------------------
// Grid 1024 (XCD-swizzled): lid = (b*32+nt)*4+chq. 512 threads = 8 waves.
// Wave w: q-rows [nt*128+w*16, +16), all 128 ch of quarter chq.
__global__ __launch_bounds__(512, 4) void k_flash2(const u16* __restrict__ q,
    const u16* __restrict__ kk, const u16* __restrict__ v, u16* __restrict__ y)
{
  __shared__ u16 Kt[2 * 64 * 128];   // [buf][kv 64][i 128], 16B-chunk xor swz
  __shared__ u16 Vt[2 * 128 * 64];   // [buf][ch 128][kv 64], xor swz
  __shared__ u16 Pt[128 * 64];       // [q 128][kv 64], xor swz, wave-private rows

  int bid = blockIdx.x;
  int lid = (bid & 7) * 128 + (bid >> 3);        // bijective XCD chunking
  int chq = lid & 3, nt = (lid >> 2) & 31, b = lid >> 7;
  int tid = threadIdx.x, w = tid >> 6, l = tid & 63;
  int l15 = l & 15, lh = l >> 4;

  const u16* qb = q  + ((size_t)b * N_ + nt * 128) * I_;
  const u16* kb = kk + (size_t)b * N_ * I_;
  const u16* vb = v  + ((size_t)b * C_ + chq * 128) * N_;

  // Q fragments straight to registers (read once)
  half8 qf[4];
#pragma unroll
  for (int kc = 0; kc < 4; ++kc)
    qf[kc] = *(const half8*)(qb + (size_t)(w * 16 + l15) * I_ + kc * 32 + lh * 8);

  // distance constants: dy loop-invariant, dx = dxb - mt
  float qcf[4], dxb[4];
#pragma unroll
  for (int e = 0; e < 4; ++e) {
    int qloc = w * 16 + lh * 4 + e;
    qcf[e] = (float)(qloc & 63);
    dxb[e] = (float)(nt * 2 + (qloc >> 6));
  }
  const float kcf = (float)l15;

  auto STAGE = [&](int mt, int bufp) {
#pragma unroll
    for (int i = 0; i < 2; ++i) {                 // K: 64 rows x 16 chunks
      int slot = i * 512 + tid; int row = slot >> 4, ck = slot & 15;
      gld16(kb + (size_t)(mt * 64 + row) * I_ + ((ck ^ (row & 7)) << 3),
            (char*)Kt + bufp * 16384 + i * 8192 + w * 1024);
    }
#pragma unroll
    for (int i = 0; i < 2; ++i) {                 // V: 128 rows x 8 chunks
      int slot = i * 512 + tid; int row = slot >> 3, ck = slot & 7;
      gld16(vb + (size_t)row * N_ + mt * 64 + ((ck ^ (row & 7)) << 3),
            (char*)Vt + bufp * 16384 + i * 8192 + w * 1024);
    }
  };

  STAGE(0, 0);

  float mrow[4], lrow[4];
  f32x4 acc[8];
#pragma unroll
  for (int e = 0; e < 4; ++e) { mrow[e] = -3e38f; lrow[e] = 0.f; }
#pragma unroll
  for (int nj = 0; nj < 8; ++nj) acc[nj] = f32x4{0.f, 0.f, 0.f, 0.f};

#pragma unroll 1
  for (int mt = 0; mt < 64; ++mt) {
    // B1: all LDS reads of the buffer we are about to overwrite are retired
    asm volatile("s_waitcnt lgkmcnt(0)" ::: "memory");
    __builtin_amdgcn_s_barrier();
    __builtin_amdgcn_sched_barrier(0);
    if (mt < 63) {
      STAGE(mt + 1, (mt + 1) & 1);                // prefetch next tile
      __builtin_amdgcn_sched_barrier(0);
      asm volatile("s_waitcnt vmcnt(4)" ::: "memory");   // tile mt arrived
    } else {
      asm volatile("s_waitcnt vmcnt(0)" ::: "memory");
    }
    __builtin_amdgcn_sched_barrier(0);
    __builtin_amdgcn_s_barrier();                 // B2: tile mt visible to all
    __builtin_amdgcn_sched_barrier(0);

    const char* kbuf = (const char*)Kt + (mt & 1) * 16384;
    const char* vbuf = (const char*)Vt + (mt & 1) * 16384;

    // ---- QK^T: 16 q-rows x 64 kv (K=128) ----
    f32x4 s[4];
#pragma unroll
    for (int nj = 0; nj < 4; ++nj) s[nj] = f32x4{0.f, 0.f, 0.f, 0.f};
#pragma unroll
    for (int kc = 0; kc < 4; ++kc) {
#pragma unroll
      for (int nj = 0; nj < 4; ++nj) {
        int row = nj * 16 + l15;
        half8 kf = *(const half8*)(kbuf + row * 256 +
                                   ((kc * 64 + lh * 16) ^ ((row & 7) << 4)));
        s[nj] = mfma16(qf[kc], kf, s[nj]);
      }
    }

    // ---- apply 1/(1+dist): dx per e, dy per (nj,e) ----
    const float mtf = (float)mt;
#pragma unroll
    for (int e = 0; e < 4; ++e) {
      float dxv = dxb[e] - mtf;
      float dx2 = dxv * dxv;
#pragma unroll
      for (int nj = 0; nj < 4; ++nj) {
        float dy = qcf[e] - (kcf + 16.0f * nj);
        float d2 = __builtin_fmaf(dy, dy, dx2);
        float rd = __builtin_amdgcn_rcpf(1.0f + __builtin_amdgcn_sqrtf(d2));
        s[nj][e] *= rd;
      }
    }

    // ---- online softmax (wave-local rows) ----
    float m0[4]; int grew = 0;
#pragma unroll
    for (int e = 0; e < 4; ++e) {
      float m = fmaxf(fmaxf(s[0][e], s[1][e]), fmaxf(s[2][e], s[3][e]));
#pragma unroll
      for (int d = 1; d < 16; d <<= 1) m = fmaxf(m, __shfl_xor(m, d, 64));
      m0[e] = m;
      grew |= (m > mrow[e]) ? 1 : 0;
    }
    if (__any(grew)) {
      float al[4];
#pragma unroll
      for (int e = 0; e < 4; ++e) {
        float mn = fmaxf(mrow[e], m0[e]);
        al[e] = __expf(mrow[e] - mn);
        mrow[e] = mn;
        lrow[e] *= al[e];
      }
#pragma unroll
      for (int nj = 0; nj < 8; ++nj)
#pragma unroll
        for (int e = 0; e < 4; ++e) acc[nj][e] *= al[e];
    }

    // ---- P = exp(S-m) -> Pt (wave-private rows), rowsum ----
#pragma unroll
    for (int e = 0; e < 4; ++e) {
      int row = w * 16 + lh * 4 + e;
      float ps = 0.f;
#pragma unroll
      for (int nj = 0; nj < 4; ++nj) {
        float p = __expf(s[nj][e] - mrow[e]);
        ps += p;
        int byte = row * 128 + ((nj * 32 + l15 * 2) ^ ((row & 7) << 4));
        *(u16*)((char*)Pt + byte) = f2h(p);
      }
#pragma unroll
      for (int d = 1; d < 16; d <<= 1) ps += __shfl_xor(ps, d, 64);
      lrow[e] += ps;
    }

    // ---- PV: acc += P @ V^T (K = 64) ----
#pragma unroll
    for (int kc = 0; kc < 2; ++kc) {
      int prow = w * 16 + l15;
      half8 pa = *(const half8*)((const char*)Pt + prow * 128 +
                                 ((kc * 64 + lh * 16) ^ ((prow & 7) << 4)));
#pragma unroll
      for (int nj = 0; nj < 8; ++nj) {
        int vrow = nj * 16 + l15;
        half8 vf = *(const half8*)(vbuf + vrow * 128 +
                                   ((kc * 64 + lh * 16) ^ ((vrow & 7) << 4)));
        acc[nj] = mfma16(pa, vf, acc[nj]);
      }
    }
  }

  // ---- epilogue: y = acc / rowsum ----
#pragma unroll
  for (int e = 0; e < 4; ++e) {
    float inv = __builtin_amdgcn_rcpf(lrow[e]);
    int gn = nt * 128 + w * 16 + lh * 4 + e;
#pragma unroll
    for (int nj = 0; nj < 8; ++nj) {
      int gc = chq * 128 + nj * 16 + l15;
      y[((size_t)b * N_ + gn) * C_ + gc] = f2h(acc[nj][e] * inv);
    }
  }
}

// ---------------- u = Wu @ y^T, + BN partial stats ----------------------------
__global__ __launch_bounds__(256) void k_u(const u16* __restrict__ wu,
    const u16* __restrict__ y, u16* __restrict__ uo, float* __restrict__ stats)
{
  __shared__ u16 As[128 * 32], Bs[128 * 32];
  int id = blockIdx.x;
  int bm = id & 3, bn = (id >> 2) & 31, b = id >> 7;
  const u16* Ap = wu + bm * 128 * 512;
  const u16* Bp = y + (size_t)b * N_ * C_ + (size_t)bn * 128 * C_;
  f32x4 acc[4][4];
#pragma unroll
  for (int a1 = 0; a1 < 4; ++a1)
#pragma unroll
    for (int a2 = 0; a2 < 4; ++a2) acc[a1][a2] = f32x4{0.f, 0.f, 0.f, 0.f};
  gemm128_bt(Ap, 512, Bp, 512, 512, As, Bs, acc);

  int tid = threadIdx.x, w = tid >> 6, l = tid & 63, wr = w >> 1, wc = w & 1;
#pragma unroll
  for (int mi = 0; mi < 4; ++mi)
#pragma unroll
    for (int e = 0; e < 4; ++e) {
      int gr = bm * 128 + wr * 64 + mi * 16 + ((l >> 4) << 2) + e;
      float s = 0.f, s2 = 0.f;
#pragma unroll
      for (int nj = 0; nj < 4; ++nj) {
        float val = acc[mi][nj][e];
        int gc = bn * 128 + wc * 64 + nj * 16 + (l & 15);
        uo[((size_t)b * C_ + gr) * N_ + gc] = f2h(val);
        s += val; s2 += val * val;
      }
#pragma unroll
      for (int d = 1; d < 16; d <<= 1) {
        s  += __shfl_xor(s, d, 64);
        s2 += __shfl_xor(s2, d, 64);
      }
      if ((l & 15) == 0) {
        atomicAdd(stats + gr, s);
        atomicAdd(stats + 512 + gr, s2);
      }
    }
}

// ---------------- BN finalize -------------------------------------------------
__global__ __launch_bounds__(256) void k_bnfin(const float* __restrict__ stats,
    const float* __restrict__ gamma, const float* __restrict__ beta,
    float* __restrict__ coef)
{
  int c = blockIdx.x * 256 + threadIdx.x;
  if (c < 512) {
    const float inv = 1.0f / (float)(B_ * N_);
    float mean = stats[c] * inv;
    float var = stats[512 + c] * inv - mean * mean;
    float sc = gamma[c] * rsqrtf(var + 1e-5f);
    coef[c] = sc;
    coef[512 + c] = beta[c] - mean * sc;
  }
}

// ---------------- epilogue: relu(u_bn + x) ------------------------------------
__global__ __launch_bounds__(256) void k_out(const u16* __restrict__ uo,
    const float* __restrict__ x, const float* __restrict__ coef,
    float* __restrict__ out)
{
  int t = blockIdx.x * 256 + threadIdx.x;
  size_t base = (size_t)t * 8;
  int c = (t >> 9) & 511;
  float sc = coef[c], sh = coef[512 + c];
  using short8 = __attribute__((ext_vector_type(8))) short;
  short8 uv = *(const short8*)(uo + base);
  const float4* xp = (const float4*)(x + base);
  float4 x0 = xp[0], x1 = xp[1];
  float4 o0, o1;
  o0.x = fmaxf(h2f((u16)uv[0]) * sc + sh + x0.x, 0.f);
  o0.y = fmaxf(h2f((u16)uv[1]) * sc + sh + x0.y, 0.f);
  o0.z = fmaxf(h2f((u16)uv[2]) * sc + sh + x0.z, 0.f);
  o0.w = fmaxf(h2f((u16)uv[3]) * sc + sh + x0.w, 0.f);
  o1.x = fmaxf(h2f((u16)uv[4]) * sc + sh + x1.x, 0.f);
  o1.y = fmaxf(h2f((u16)uv[5]) * sc + sh + x1.y, 0.f);
  o1.z = fmaxf(h2f((u16)uv[6]) * sc + sh + x1.z, 0.f);
  o1.w = fmaxf(h2f((u16)uv[7]) * sc + sh + x1.w, 0.f);
  float4* op = (float4*)(out + base);
  op[0] = o0; op[1] = o1;
}

// ---------------- launcher ----------------------------------------------------
extern "C" void kernel_launch(void* const* d_in, const int* in_sizes, int n_in,
                              void* d_out, int out_size, void* d_ws, size_t ws_size,
                              hipStream_t stream)
{
  const float* x  = (const float*)d_in[0];
  const float* Wv = (const float*)d_in[1];
  const float* Wq = (const float*)d_in[2];
  const float* Wk = (const float*)d_in[3];
  const float* Wu = (const float*)d_in[4];
  const float* gm = (const float*)d_in[5];
  const float* bt = (const float*)d_in[6];

  char* ws = (char*)d_ws;
  u16* xt       = (u16*)(ws + 0);            // 33,554,432 (xt, then y)
  u16* y        = xt;
  u16* v        = (u16*)(ws + 33554432);     // 33,554,432
  u16* q        = (u16*)(ws + 67108864);     //  8,388,608
  u16* kk       = (u16*)(ws + 75497472);     //  8,388,608
  u16* wqkv     = (u16*)(ws + 83886080);     //    786,432
  u16* wu       = (u16*)(ws + 84672512);     //    524,288
  float* stats  = (float*)(ws + 85196800);   //      4,096
  float* coef   = (float*)(ws + 85200896);   //      4,096
  u16* uo       = (u16*)(ws + 85204992);     // 33,554,432
  // total ~113 MB

  k_init<<<1536, 256, 0, stream>>>(Wv, Wq, Wk, Wu, wqkv, wu, stats);
  k_xt<<<4096, 256, 0, stream>>>(x, xt);
  k_proj<<<1536, 256, 0, stream>>>(wqkv, xt, v, q, kk);
  k_flash2<<<1024, 512, 0, stream>>>(q, kk, v, y);
  k_u<<<1024, 256, 0, stream>>>(wu, y, uo, stats);
  k_bnfin<<<2, 256, 0, stream>>>(stats, gm, bt, coef);
  k_out<<<8192, 256, 0, stream>>>(uo, x, coef, (float*)d_out);
}

// Round 7
// 637.138 us; speedup vs baseline: 2.2232x; 1.3826x over previous
//
#include <hip/hip_runtime.h>
#include <cstdint>

// NonLocalBlock MI355X — flash-fused attention v4 (fp16 MFMA, fp32 accum).
// k_flash4: block=(b,nt) computes S ONCE for all 512 ch. 8 waves; wave w owns
//   q-rows [nt*128+w*16,+16) x all 512 ch. KVBLK=32, K/V double-buffered LDS,
//   counted vmcnt(5) prefetch (v2-proven pipeline). v2-proven fragment paths:
//   A=Q rows / B=K cols QK^T, 4-shfl softmax over l15, rescale-on-grew,
//   scalar u16 P writes with f(row)=(row&3)<<4 XOR pairing, PV A=P B=V^T.
// LDS: K 2x8K + V 2x32K + P 8K = 88KB.

typedef unsigned short u16;
typedef unsigned int u32;
using half8 = __attribute__((ext_vector_type(8))) _Float16;
using f32x4 = __attribute__((ext_vector_type(4))) float;

#define B_ 8
#define N_ 4096
#define C_ 512
#define I_ 128

__device__ __forceinline__ u16 f2h(float f) {
  return __builtin_bit_cast(u16, (_Float16)f);
}
__device__ __forceinline__ float h2f(u16 v) {
  return (float)__builtin_bit_cast(_Float16, v);
}

__device__ __forceinline__ void gld16(const void* g, void* l) {
  __builtin_amdgcn_global_load_lds((const __attribute__((address_space(1))) u32*)g,
                                   (__attribute__((address_space(3))) u32*)l, 16, 0, 0);
}

__device__ __forceinline__ f32x4 mfma16(half8 a, half8 b, f32x4 c) {
  return __builtin_amdgcn_mfma_f32_16x16x32_f16(a, b, c, 0, 0, 0);
}

// ---------------- common 128x128 BT-GEMM core (BK=32, 256 threads, 4 waves) ---
__device__ __forceinline__ void gemm128_bt(const u16* __restrict__ Ap, int lda,
                                           const u16* __restrict__ Bp, int ldb,
                                           int K, u16* As, u16* Bs,
                                           f32x4 (&acc)[4][4])
{
  const int tid = threadIdx.x;
  const int w = tid >> 6, l = tid & 63;
  const int wr = w >> 1, wc = w & 1;
  const int srow = tid >> 2, schunk = tid & 3;

  for (int k0 = 0; k0 < K; k0 += 32) {
    __syncthreads();
#pragma unroll
    for (int i = 0; i < 2; ++i) {
      int r = i * 64 + srow;
      int sc = (schunk ^ (r & 3) ^ ((r >> 2) & 3)) << 3;
      gld16(Ap + (size_t)r * lda + k0 + sc, As + i * 2048 + w * 512);
      gld16(Bp + (size_t)r * ldb + k0 + sc, Bs + i * 2048 + w * 512);
    }
    __syncthreads();

    half8 af[4], bf[4];
#pragma unroll
    for (int mi = 0; mi < 4; ++mi) {
      int rl = wr * 64 + mi * 16 + (l & 15);
      int ch = (l >> 4) ^ (rl & 3) ^ ((rl >> 2) & 3);
      af[mi] = *(const half8*)(As + rl * 32 + ch * 8);
    }
#pragma unroll
    for (int nj = 0; nj < 4; ++nj) {
      int rl = wc * 64 + nj * 16 + (l & 15);
      int ch = (l >> 4) ^ (rl & 3) ^ ((rl >> 2) & 3);
      bf[nj] = *(const half8*)(Bs + rl * 32 + ch * 8);
    }
#pragma unroll
    for (int mi = 0; mi < 4; ++mi)
#pragma unroll
      for (int nj = 0; nj < 4; ++nj)
        acc[mi][nj] = mfma16(af[mi], bf[nj], acc[mi][nj]);
  }
}

// ---------------- init ---------------------------------------------------------
__global__ __launch_bounds__(256) void k_init(const float* __restrict__ Wv,
    const float* __restrict__ Wq, const float* __restrict__ Wk,
    const float* __restrict__ Wu, u16* __restrict__ wqkv, u16* __restrict__ wu,
    float* __restrict__ stats)
{
  int i = blockIdx.x * 256 + threadIdx.x;
  if (i < 768 * 512) {
    int r = i >> 9, c = i & 511;
    float val = (r < 512) ? Wv[i] : (r < 640 ? Wq[(r - 512) * 512 + c]
                                             : Wk[(r - 640) * 512 + c]);
    wqkv[i] = f2h(val);
  }
  if (i < 512 * 512) wu[i] = f2h(Wu[i]);
  if (i < 1024) stats[i] = 0.f;
}

// ---------------- x transpose+convert ----------------------------------------
__global__ __launch_bounds__(256) void k_xt(const float* __restrict__ x,
                                            u16* __restrict__ xt)
{
  __shared__ float t[64][65];
  int id = blockIdx.x;
  int b = id >> 9, cg = (id >> 6) & 7, ng = id & 63;
  int c0 = cg * 64, n0 = ng * 64;
  int tid = threadIdx.x;
  const float* xs = x + ((size_t)b * C_ + c0) * N_ + n0;
#pragma unroll
  for (int p = 0; p < 16; ++p) {
    int idx = p * 256 + tid; int r = idx >> 6, cl = idx & 63;
    t[r][cl] = xs[(size_t)r * N_ + cl];
  }
  __syncthreads();
  u16* xd = xt + ((size_t)b * N_ + n0) * C_ + c0;
#pragma unroll
  for (int p = 0; p < 16; ++p) {
    int idx = p * 256 + tid; int r = idx >> 6, cl = idx & 63;
    xd[(size_t)r * C_ + cl] = f2h(t[cl][r]);
  }
}

// ---------------- fused QKV projection ---------------------------------------
__global__ __launch_bounds__(256) void k_proj(const u16* __restrict__ wqkv,
    const u16* __restrict__ xt, u16* __restrict__ v, u16* __restrict__ q,
    u16* __restrict__ kk)
{
  __shared__ u16 As[128 * 32], Bs[128 * 32];
  int id = blockIdx.x;
  int bm = id % 6; int rest = id / 6; int bn = rest & 31; int b = rest >> 5;
  const u16* Ap = wqkv + bm * 128 * 512;
  const u16* Bp = xt + ((size_t)b * N_ + bn * 128) * C_;
  f32x4 acc[4][4];
#pragma unroll
  for (int a1 = 0; a1 < 4; ++a1)
#pragma unroll
    for (int a2 = 0; a2 < 4; ++a2) acc[a1][a2] = f32x4{0.f, 0.f, 0.f, 0.f};
  gemm128_bt(Ap, 512, Bp, 512, 512, As, Bs, acc);

  int tid = threadIdx.x, w = tid >> 6, l = tid & 63, wr = w >> 1, wc = w & 1;
#pragma unroll
  for (int mi = 0; mi < 4; ++mi)
#pragma unroll
    for (int nj = 0; nj < 4; ++nj)
#pragma unroll
      for (int e = 0; e < 4; ++e) {
        int gr = bm * 128 + wr * 64 + mi * 16 + ((l >> 4) << 2) + e;
        int gc = bn * 128 + wc * 64 + nj * 16 + (l & 15);
        u16 bv = f2h(acc[mi][nj][e]);
        if (bm < 4)       v[((size_t)b * C_ + gr) * N_ + gc] = bv;
        else if (bm == 4) q[((size_t)b * N_ + gc) * I_ + (gr - 512)] = bv;
        else              kk[((size_t)b * N_ + gc) * I_ + (gr - 640)] = bv;
      }
}

// ---------------- flash attention v4 -----------------------------------------
// Grid 256 = (b, nt), XCD-chunked. 512 threads = 8 waves; wave w owns q-rows
// [nt*128+w*16,+16) and ALL 512 ch. v2-proven orientations throughout.
__global__ __launch_bounds__(512, 2) void k_flash4(const u16* __restrict__ q,
    const u16* __restrict__ kk, const u16* __restrict__ v, u16* __restrict__ y)
{
  __shared__ u16 Kt[2 * 32 * 128];   // [buf][kv 32][i 128] 256B rows, swz row&7
  __shared__ u16 Vt[2 * 512 * 32];   // [buf][ch 512][kv 32] 64B rows, swz row&3
  __shared__ u16 Pt[128 * 32];       // [q 128][kv 32] 64B rows, swz row&3

  int bid = blockIdx.x;
  int lid = (bid & 7) * 32 + (bid >> 3);       // bijective XCD chunking (256=8*32)
  int nt = lid & 31, b = lid >> 5;
  int tid = threadIdx.x, w = tid >> 6, l = tid & 63;
  int l15 = l & 15, lh = l >> 4;

  const u16* qb = q  + ((size_t)b * N_ + nt * 128) * I_;
  const u16* kb = kk + (size_t)b * N_ * I_;
  const u16* vb = v  + (size_t)b * C_ * N_;

  // Q A-frags: lane (lh,l15) holds Q[q=w*16+l15][i=kc*32+lh*8 .. +8]  (v2-proven)
  half8 qf[4];
#pragma unroll
  for (int kc = 0; kc < 4; ++kc)
    qf[kc] = *(const half8*)(qb + (size_t)(w * 16 + l15) * I_ + kc * 32 + lh * 8);

  // distance constants per acc-row e (q = nt*128 + w*16 + lh*4 + e)
  float qcf[4], dxb[4];
#pragma unroll
  for (int e = 0; e < 4; ++e) {
    int qi = nt * 128 + w * 16 + lh * 4 + e;
    qcf[e] = (float)(qi & 63);
    dxb[e] = (float)(qi >> 6);
  }

  auto STAGE = [&](int mt, int bufp) {
    {                                          // K: 32 rows x 16 chunks of 16B
      int row = tid >> 4, ck = tid & 15;
      gld16(kb + (size_t)(mt * 32 + row) * I_ + ((ck ^ (row & 7)) << 3),
            (char*)Kt + bufp * 8192 + w * 1024);
    }
#pragma unroll
    for (int i = 0; i < 4; ++i) {              // V: 512 rows x 4 chunks of 16B
      int slot = i * 512 + tid; int row = slot >> 2, ck = slot & 3;
      gld16(vb + (size_t)row * N_ + mt * 32 + ((ck ^ (row & 3)) << 3),
            (char*)Vt + bufp * 32768 + i * 8192 + w * 1024);
    }
  };

  STAGE(0, 0);

  float mrow[4], lrow[4];
#pragma unroll
  for (int e = 0; e < 4; ++e) { mrow[e] = -3e38f; lrow[e] = 0.f; }
  f32x4 acc[32];                                // acc[nj][e]: q=lh*4+e, ch=nj*16+l15
#pragma unroll
  for (int nj = 0; nj < 32; ++nj) acc[nj] = f32x4{0.f, 0.f, 0.f, 0.f};

#pragma unroll 1
  for (int mt = 0; mt < 128; ++mt) {
    asm volatile("s_waitcnt lgkmcnt(0)" ::: "memory");
    __builtin_amdgcn_s_barrier();              // B1: prev-iter LDS reads done
    __builtin_amdgcn_sched_barrier(0);
    if (mt < 127) {
      STAGE(mt + 1, (mt + 1) & 1);             // prefetch next tile
      __builtin_amdgcn_sched_barrier(0);
      asm volatile("s_waitcnt vmcnt(5)" ::: "memory");   // tile mt arrived
    } else {
      asm volatile("s_waitcnt vmcnt(0)" ::: "memory");
    }
    __builtin_amdgcn_sched_barrier(0);
    __builtin_amdgcn_s_barrier();              // B2: tile mt visible
    __builtin_amdgcn_sched_barrier(0);

    const char* kbuf = (const char*)Kt + (mt & 1) * 8192;
    const char* vbuf = (const char*)Vt + (mt & 1) * 32768;

    // ---- QK^T: S[q 16][kv 32], A=Q, B=K  (v2 orientation) ----
    f32x4 s[2];
    s[0] = f32x4{0.f, 0.f, 0.f, 0.f};
    s[1] = f32x4{0.f, 0.f, 0.f, 0.f};
#pragma unroll
    for (int kc = 0; kc < 4; ++kc) {
#pragma unroll
      for (int nj = 0; nj < 2; ++nj) {
        int row = nj * 16 + l15;               // kv row of K-tile
        half8 kf = *(const half8*)(kbuf + row * 256 +
                                   ((kc * 64 + lh * 16) ^ ((row & 7) << 4)));
        s[nj] = mfma16(qf[kc], kf, s[nj]);
      }
    }

    // ---- 1/(1+dist): kv = mt*32 + nj*16 + l15 ----
    const float mxf = (float)(mt >> 1);
    const float kvy0 = (float)(((mt & 1) << 5) + l15);
#pragma unroll
    for (int e = 0; e < 4; ++e) {
      float dx = dxb[e] - mxf;
      float dx2 = dx * dx;
#pragma unroll
      for (int nj = 0; nj < 2; ++nj) {
        float dy = qcf[e] - (kvy0 + 16.0f * nj);
        float d2 = __builtin_fmaf(dy, dy, dx2);
        s[nj][e] *= __builtin_amdgcn_rcpf(1.0f + __builtin_amdgcn_sqrtf(d2));
      }
    }

    // ---- online softmax per q-row e (reduce over nj + l15 lanes) ----
    float m0[4]; int grew = 0;
#pragma unroll
    for (int e = 0; e < 4; ++e) {
      float m = fmaxf(s[0][e], s[1][e]);
#pragma unroll
      for (int d = 1; d < 16; d <<= 1) m = fmaxf(m, __shfl_xor(m, d, 64));
      m0[e] = m;
      grew |= (m > mrow[e]) ? 1 : 0;
    }
    if (__any(grew)) {
      float al[4];
#pragma unroll
      for (int e = 0; e < 4; ++e) {
        float mn = fmaxf(mrow[e], m0[e]);
        al[e] = __expf(mrow[e] - mn);
        mrow[e] = mn;
        lrow[e] *= al[e];
      }
#pragma unroll
      for (int nj = 0; nj < 32; ++nj)
#pragma unroll
        for (int e = 0; e < 4; ++e) acc[nj][e] *= al[e];
    }

    // ---- P = exp(S-m) -> Pt (scalar u16, v2-proven pairing), rowsum ----
#pragma unroll
    for (int e = 0; e < 4; ++e) {
      int row = w * 16 + lh * 4 + e;           // row&3 == e
      float ps = 0.f;
#pragma unroll
      for (int nj = 0; nj < 2; ++nj) {
        float p = __expf(s[nj][e] - mrow[e]);
        ps += p;
        int byte = row * 64 + ((nj * 32 + l15 * 2) ^ ((row & 3) << 4));
        *(u16*)((char*)Pt + byte) = f2h(p);
      }
#pragma unroll
      for (int d = 1; d < 16; d <<= 1) ps += __shfl_xor(ps, d, 64);
      lrow[e] += ps;
    }

    // ---- PV: acc += P @ V^T (K=32), A=P rows q, B=V^T cols ch ----
    int prow = w * 16 + l15;
    half8 pa = *(const half8*)((const char*)Pt + prow * 64 +
                               ((lh * 16) ^ ((prow & 3) << 4)));
#pragma unroll
    for (int nj = 0; nj < 32; ++nj) {
      int vrow = nj * 16 + l15;
      half8 vf = *(const half8*)(vbuf + vrow * 64 +
                                 ((lh * 16) ^ ((vrow & 3) << 4)));
      acc[nj] = mfma16(pa, vf, acc[nj]);
    }
  }

  // ---- epilogue: y = acc / rowsum (lrow[e] is this lane's q-row, v2-style) ----
#pragma unroll
  for (int e = 0; e < 4; ++e) {
    float li = 1.0f / lrow[e];
    u16* yr = y + ((size_t)b * N_ + nt * 128 + w * 16 + lh * 4 + e) * C_;
#pragma unroll
    for (int nj = 0; nj < 32; ++nj)
      yr[nj * 16 + l15] = f2h(acc[nj][e] * li);
  }
}

// ---------------- u = Wu @ y^T, + BN partial stats ----------------------------
__global__ __launch_bounds__(256) void k_u(const u16* __restrict__ wu,
    const u16* __restrict__ y, u16* __restrict__ uo, float* __restrict__ stats)
{
  __shared__ u16 As[128 * 32], Bs[128 * 32];
  int id = blockIdx.x;
  int bm = id & 3, bn = (id >> 2) & 31, b = id >> 7;
  const u16* Ap = wu + bm * 128 * 512;
  const u16* Bp = y + (size_t)b * N_ * C_ + (size_t)bn * 128 * C_;
  f32x4 acc[4][4];
#pragma unroll
  for (int a1 = 0; a1 < 4; ++a1)
#pragma unroll
    for (int a2 = 0; a2 < 4; ++a2) acc[a1][a2] = f32x4{0.f, 0.f, 0.f, 0.f};
  gemm128_bt(Ap, 512, Bp, 512, 512, As, Bs, acc);

  int tid = threadIdx.x, w = tid >> 6, l = tid & 63, wr = w >> 1, wc = w & 1;
#pragma unroll
  for (int mi = 0; mi < 4; ++mi)
#pragma unroll
    for (int e = 0; e < 4; ++e) {
      int gr = bm * 128 + wr * 64 + mi * 16 + ((l >> 4) << 2) + e;
      float s = 0.f, s2 = 0.f;
#pragma unroll
      for (int nj = 0; nj < 4; ++nj) {
        float val = acc[mi][nj][e];
        int gc = bn * 128 + wc * 64 + nj * 16 + (l & 15);
        uo[((size_t)b * C_ + gr) * N_ + gc] = f2h(val);
        s += val; s2 += val * val;
      }
#pragma unroll
      for (int d = 1; d < 16; d <<= 1) {
        s  += __shfl_xor(s, d, 64);
        s2 += __shfl_xor(s2, d, 64);
      }
      if ((l & 15) == 0) {
        atomicAdd(stats + gr, s);
        atomicAdd(stats + 512 + gr, s2);
      }
    }
}

// ---------------- BN finalize -------------------------------------------------
__global__ __launch_bounds__(256) void k_bnfin(const float* __restrict__ stats,
    const float* __restrict__ gamma, const float* __restrict__ beta,
    float* __restrict__ coef)
{
  int c = blockIdx.x * 256 + threadIdx.x;
  if (c < 512) {
    const float inv = 1.0f / (float)(B_ * N_);
    float mean = stats[c] * inv;
    float var = stats[512 + c] * inv - mean * mean;
    float sc = gamma[c] * rsqrtf(var + 1e-5f);
    coef[c] = sc;
    coef[512 + c] = beta[c] - mean * sc;
  }
}

// ---------------- epilogue: relu(u_bn + x) ------------------------------------
__global__ __launch_bounds__(256) void k_out(const u16* __restrict__ uo,
    const float* __restrict__ x, const float* __restrict__ coef,
    float* __restrict__ out)
{
  int t = blockIdx.x * 256 + threadIdx.x;
  size_t base = (size_t)t * 8;
  int c = (t >> 9) & 511;
  float sc = coef[c], sh = coef[512 + c];
  using short8 = __attribute__((ext_vector_type(8))) short;
  short8 uv = *(const short8*)(uo + base);
  const float4* xp = (const float4*)(x + base);
  float4 x0 = xp[0], x1 = xp[1];
  float4 o0, o1;
  o0.x = fmaxf(h2f((u16)uv[0]) * sc + sh + x0.x, 0.f);
  o0.y = fmaxf(h2f((u16)uv[1]) * sc + sh + x0.y, 0.f);
  o0.z = fmaxf(h2f((u16)uv[2]) * sc + sh + x0.z, 0.f);
  o0.w = fmaxf(h2f((u16)uv[3]) * sc + sh + x0.w, 0.f);
  o1.x = fmaxf(h2f((u16)uv[4]) * sc + sh + x1.x, 0.f);
  o1.y = fmaxf(h2f((u16)uv[5]) * sc + sh + x1.y, 0.f);
  o1.z = fmaxf(h2f((u16)uv[6]) * sc + sh + x1.z, 0.f);
  o1.w = fmaxf(h2f((u16)uv[7]) * sc + sh + x1.w, 0.f);
  float4* op = (float4*)(out + base);
  op[0] = o0; op[1] = o1;
}

// ---------------- launcher ----------------------------------------------------
extern "C" void kernel_launch(void* const* d_in, const int* in_sizes, int n_in,
                              void* d_out, int out_size, void* d_ws, size_t ws_size,
                              hipStream_t stream)
{
  const float* x  = (const float*)d_in[0];
  const float* Wv = (const float*)d_in[1];
  const float* Wq = (const float*)d_in[2];
  const float* Wk = (const float*)d_in[3];
  const float* Wu = (const float*)d_in[4];
  const float* gm = (const float*)d_in[5];
  const float* bt = (const float*)d_in[6];

  char* ws = (char*)d_ws;
  u16* xt       = (u16*)(ws + 0);            // 33,554,432 (xt, then y)
  u16* y        = xt;
  u16* v        = (u16*)(ws + 33554432);     // 33,554,432
  u16* q        = (u16*)(ws + 67108864);     //  8,388,608
  u16* kk       = (u16*)(ws + 75497472);     //  8,388,608
  u16* wqkv     = (u16*)(ws + 83886080);     //    786,432
  u16* wu       = (u16*)(ws + 84672512);     //    524,288
  float* stats  = (float*)(ws + 85196800);   //      4,096
  float* coef   = (float*)(ws + 85200896);   //      4,096
  u16* uo       = (u16*)(ws + 85204992);     // 33,554,432
  // total ~113 MB

  k_init<<<1536, 256, 0, stream>>>(Wv, Wq, Wk, Wu, wqkv, wu, stats);
  k_xt<<<4096, 256, 0, stream>>>(x, xt);
  k_proj<<<1536, 256, 0, stream>>>(wqkv, xt, v, q, kk);
  k_flash4<<<256, 512, 0, stream>>>(q, kk, v, y);
  k_u<<<1024, 256, 0, stream>>>(wu, y, uo, stats);
  k_bnfin<<<2, 256, 0, stream>>>(stats, gm, bt, coef);
  k_out<<<8192, 256, 0, stream>>>(uo, x, coef, (float*)d_out);
}